// Round 3
// baseline (270.603 us; speedup 1.0000x reference)
//
#include <hip/hip_runtime.h>
#include <cstdint>

// ---------- types & helpers ----------
typedef __attribute__((ext_vector_type(8))) short short8_t;
typedef __attribute__((ext_vector_type(8))) __bf16 bf16x8_t;
typedef __attribute__((ext_vector_type(4))) float f32x4_t;

__device__ __forceinline__ float bf2f(unsigned short u) {
  return __uint_as_float(((unsigned)u) << 16);
}
__device__ __forceinline__ unsigned short f2bf(float f) {
  unsigned u = __float_as_uint(f);
  u += 0x7FFFu + ((u >> 16) & 1u);
  return (unsigned short)(u >> 16);
}

// MFMA wrapper: tolerate either builtin signature (short8 or bf16x8 operands).
template <typename V>
__device__ __forceinline__ auto mfma16_impl(V a, V b, f32x4_t c, int)
    -> decltype(__builtin_amdgcn_mfma_f32_16x16x32_bf16(a, b, c, 0, 0, 0)) {
  return __builtin_amdgcn_mfma_f32_16x16x32_bf16(a, b, c, 0, 0, 0);
}
template <typename V>
__device__ __forceinline__ f32x4_t mfma16_impl(V a, V b, f32x4_t c, long) {
  bf16x8_t ab = __builtin_bit_cast(bf16x8_t, a);
  bf16x8_t bb = __builtin_bit_cast(bf16x8_t, b);
  return __builtin_amdgcn_mfma_f32_16x16x32_bf16(ab, bb, c, 0, 0, 0);
}
__device__ __forceinline__ f32x4_t MFMA16(short8_t a, short8_t b, f32x4_t c) {
  return mfma16_impl(a, b, c, 0);
}

#define PITCH 40  // 64x32 bf16 tile rows padded 32->40 elems (80B): conflict-light b128 reads

#define GEMM_VARS                                                       \
  __shared__ __align__(16) short Als[64 * PITCH];                       \
  __shared__ __align__(16) short Bls[64 * PITCH];                       \
  const int tid = threadIdx.x;                                          \
  const int lane = tid & 63;                                            \
  const int wv = tid >> 6;                                              \
  const int mw = (wv >> 1) << 5;                                        \
  const int nw = (wv & 1) << 5;                                         \
  const int fr = lane & 15;                                             \
  const int fq = lane >> 4;                                             \
  const int sr = tid >> 2;                                              \
  const int sc = (tid & 3) << 3;                                        \
  f32x4_t acc00 = {0.f, 0.f, 0.f, 0.f};                                 \
  f32x4_t acc01 = acc00, acc10 = acc00, acc11 = acc00;

#define MFMA_STEP()                                                     \
  do {                                                                  \
    const short* ap_ = &Als[(mw + fr) * PITCH + fq * 8];                \
    const short* bp_ = &Bls[(nw + fr) * PITCH + fq * 8];                \
    short8_t a0_ = *(const short8_t*)ap_;                               \
    short8_t a1_ = *(const short8_t*)(ap_ + 16 * PITCH);                \
    short8_t b0_ = *(const short8_t*)bp_;                               \
    short8_t b1_ = *(const short8_t*)(bp_ + 16 * PITCH);                \
    acc00 = MFMA16(a0_, b0_, acc00);                                    \
    acc01 = MFMA16(a0_, b1_, acc01);                                    \
    acc10 = MFMA16(a1_, b0_, acc10);                                    \
    acc11 = MFMA16(a1_, b1_, acc11);                                    \
  } while (0)

// Body sees: ml (local m), nl (local n), vv (float value). Variadic for commas.
#define GEMM_EPILOGUE(...)                                              \
  {                                                                     \
    const f32x4_t accs_[4] = {acc00, acc01, acc10, acc11};              \
    _Pragma("unroll") for (int im_ = 0; im_ < 2; ++im_)                 \
    _Pragma("unroll") for (int jn_ = 0; jn_ < 2; ++jn_) {               \
      f32x4_t aa_ = accs_[im_ * 2 + jn_];                               \
      const int ml0_ = mw + im_ * 16 + fq * 4;                          \
      const int nl = nw + jn_ * 16 + fr;                                \
      _Pragma("unroll") for (int r_ = 0; r_ < 4; ++r_) {                \
        const int ml = ml0_ + r_;                                       \
        const float vv = aa_[r_];                                       \
        __VA_ARGS__;                                                    \
      }                                                                 \
    }                                                                   \
  }

// ---------- K-1: dtype detector ----------
// If d_in holds f32 data, reading it as bf16 gives wild exponents on the
// garbage halves; genuine bf16 N(0,1) data stays in a sane range.
__global__ void k_detect(const void* q, int* flag) {
  if (threadIdx.x == 0 && blockIdx.x == 0) {
    const unsigned short* p = (const unsigned short*)q;
    int weird = 0;
    for (int i = 0; i < 512; ++i) {
      float v = bf2f(p[i]);
      float av = fabsf(v);
      if (!(av <= 1e4f) || (v != 0.f && av < 1e-10f)) ++weird;  // NaN fails av<=1e4
    }
    *flag = (weird > 40) ? 1 : 0;  // 1 = inputs are f32
  }
}

__device__ __forceinline__ unsigned short load_as_bf16(const void* p, size_t i, int f32mode) {
  return f32mode ? f2bf(((const float*)p)[i]) : ((const unsigned short*)p)[i];
}

// ---------- K0: convert activations + biases to canonical bf16 ----------
struct ConvArgs {
  const void* src[9];
  unsigned short* dst[9];
  int n[9];
};

__global__ __launch_bounds__(256) void k_convert(ConvArgs a, const int* flag) {
  const int z = blockIdx.z;
  const int n = a.n[z];
  const int f32mode = *flag;
  const int stride = gridDim.x * blockDim.x;
  for (int i = blockIdx.x * blockDim.x + threadIdx.x; i < n; i += stride)
    a.dst[z][i] = load_as_bf16(a.src[z], i, f32mode);
}

// ---------- K1: transpose all 6 weight matrices (K x 512 -> 512 x K) ----------
struct TransArgs {
  const void* src[6];
  unsigned short* dst[6];
  int K[6];
};

__global__ __launch_bounds__(256) void k_transpose(TransArgs args, const int* flag) {
  const int z = blockIdx.z;
  const int K = args.K[z];
  const int k0 = blockIdx.y * 32, n0 = blockIdx.x * 32;
  if (k0 >= K) return;
  const int f32mode = *flag;
  __shared__ unsigned short t[32][33];
  const int tx = threadIdx.x & 31, ty = threadIdx.x >> 5;  // ty 0..7
  const void* s = args.src[z];
#pragma unroll
  for (int i = 0; i < 4; ++i)
    t[ty + i * 8][tx] = load_as_bf16(s, (size_t)(k0 + ty + i * 8) * 512 + n0 + tx, f32mode);
  __syncthreads();
  unsigned short* d = args.dst[z];
#pragma unroll
  for (int i = 0; i < 4; ++i)
    d[(size_t)(n0 + ty + i * 8) * K + k0 + tx] = t[tx][ty + i * 8];
}

// ---------- K2: five projections, one kernel (blockIdx.z = op) ----------
struct ProjArgs {
  const unsigned short* A[5];
  const unsigned short* W[5];  // transposed weights (512 x 1024 row-major)
  const unsigned short* bias[5];
  unsigned short* out[5];
};

__global__ __launch_bounds__(256) void k_proj(ProjArgs args) {
  const int op = blockIdx.z;
  const int by = blockIdx.y;
  if (op != 0 && by >= 16) return;  // only op0 has M=2048; others M=1024
  const int m0 = by * 64, n0 = blockIdx.x * 64;
  const unsigned short* A = args.A[op];
  const unsigned short* W = args.W[op];
  GEMM_VARS;
  for (int k0 = 0; k0 < 1024; k0 += 32) {
    uint4 av = *(const uint4*)&A[(size_t)(m0 + sr) * 1024 + k0 + sc];
    uint4 bv = *(const uint4*)&W[(size_t)(n0 + sr) * 1024 + k0 + sc];
    __syncthreads();
    *(uint4*)&Als[sr * PITCH + sc] = av;
    *(uint4*)&Bls[sr * PITCH + sc] = bv;
    __syncthreads();
    MFMA_STEP();
  }
  const float scale = (op == 0) ? 0.044194173824159216f : 1.0f;
  const unsigned short* bias = args.bias[op];
  unsigned short* out = args.out[op];
  GEMM_EPILOGUE({
    const float v = (vv + bf2f(bias[n0 + nl])) * scale;
    const int m = m0 + ml;
    const int n = n0 + nl;
    if (op < 3) {
      out[(size_t)m * 512 + n] = f2bf(v);
    } else {
      const int bb = m >> 6;
      const int ss = m & 63;  // rows are b*64+s, one b per block
      out[(size_t)bb * 32768 + (size_t)n * 64 + ss] = f2bf(v);
    }
  });
}

// ---------- K3: scores[b,l,st] = q_s[b,l,:] . (s_key[b,s,:]*t_key[b,t,:]) ----------
__global__ __launch_bounds__(256) void k_scores(
    const unsigned short* __restrict__ qs, const unsigned short* __restrict__ skey,
    const unsigned short* __restrict__ tkey, unsigned short* __restrict__ scores) {
  const int b = blockIdx.z;
  const int m0 = blockIdx.y * 64;
  const int s0 = blockIdx.x;
  GEMM_VARS;
  const unsigned short* qbase = qs + ((size_t)b * 128 + m0) * 512;
  const unsigned short* tkb = tkey + (size_t)b * 64 * 512;
  const unsigned short* skb = skey + ((size_t)b * 64 + s0) * 512;
  for (int k0 = 0; k0 < 512; k0 += 32) {
    uint4 av = *(const uint4*)&qbase[(size_t)sr * 512 + k0 + sc];
    uint4 tv = *(const uint4*)&tkb[(size_t)sr * 512 + k0 + sc];
    uint4 sv = *(const uint4*)&skb[k0 + sc];
    union { uint4 q; unsigned short u[8]; } ut, us, up;
    ut.q = tv; us.q = sv;
#pragma unroll
    for (int j = 0; j < 8; ++j) up.u[j] = f2bf(bf2f(ut.u[j]) * bf2f(us.u[j]));
    __syncthreads();
    *(uint4*)&Als[sr * PITCH + sc] = av;
    *(uint4*)&Bls[sr * PITCH + sc] = up.q;
    __syncthreads();
    MFMA_STEP();
  }
  unsigned short* out = scores + ((size_t)b * 128 + m0) * 4096 + (size_t)s0 * 64;
  GEMM_EPILOGUE({ out[(size_t)ml * 4096 + nl] = f2bf(vv); });
}

// ---------- K4: in-place softmax over each row of 4096 ----------
__global__ __launch_bounds__(256) void k_softmax(unsigned short* __restrict__ s) {
  unsigned short* p = s + (size_t)blockIdx.x * 4096;
  const int t = threadIdx.x;
  union U8 { uint4 q; unsigned short u[8]; };
  U8 a, b;
  a.q = *(const uint4*)&p[t * 16];
  b.q = *(const uint4*)&p[t * 16 + 8];
  float x[16];
#pragma unroll
  for (int j = 0; j < 8; ++j) { x[j] = bf2f(a.u[j]); x[8 + j] = bf2f(b.u[j]); }
  float m = x[0];
#pragma unroll
  for (int j = 1; j < 16; ++j) m = fmaxf(m, x[j]);
  for (int off = 32; off > 0; off >>= 1) m = fmaxf(m, __shfl_xor(m, off));
  __shared__ float redm[4], reds[4];
  if ((t & 63) == 0) redm[t >> 6] = m;
  __syncthreads();
  m = fmaxf(fmaxf(redm[0], redm[1]), fmaxf(redm[2], redm[3]));
  float sum = 0.f;
#pragma unroll
  for (int j = 0; j < 16; ++j) { x[j] = __expf(x[j] - m); sum += x[j]; }
  for (int off = 32; off > 0; off >>= 1) sum += __shfl_xor(sum, off);
  if ((t & 63) == 0) reds[t >> 6] = sum;
  __syncthreads();
  sum = reds[0] + reds[1] + reds[2] + reds[3];
  const float inv = 1.0f / sum;
#pragma unroll
  for (int j = 0; j < 8; ++j) {
    a.u[j] = f2bf(x[j] * inv);
    b.u[j] = f2bf(x[8 + j] * inv);
  }
  *(uint4*)&p[t * 16] = a.q;
  *(uint4*)&p[t * 16 + 8] = b.q;
}

// ---------- K5: ctx[b,l,k] = sum_st p[b,l,st] * sv[b,s,k]*tv[b,t,k] ----------
__global__ __launch_bounds__(256) void k_ctx(
    const unsigned short* __restrict__ p, const unsigned short* __restrict__ svT,
    const unsigned short* __restrict__ tvT, unsigned short* __restrict__ ctx) {
  const int b = blockIdx.z;
  const int m0 = blockIdx.y * 64;
  const int n0 = blockIdx.x * 64;
  GEMM_VARS;
  const unsigned short* pbase = p + ((size_t)b * 128 + m0) * 4096;
  const unsigned short* svb = svT + (size_t)b * 32768;
  const unsigned short* tvb = tvT + (size_t)b * 32768;
  for (int ks = 0; ks < 128; ++ks) {
    const int st0 = ks * 32;
    const int s0 = st0 >> 6;
    const int t0 = st0 & 63;  // 0 or 32; K-step never straddles an s boundary
    uint4 av = *(const uint4*)&pbase[(size_t)sr * 4096 + st0 + sc];
    uint4 tv = *(const uint4*)&tvb[(size_t)(n0 + sr) * 64 + t0 + sc];
    const float svf = bf2f(svb[(size_t)(n0 + sr) * 64 + s0]);
    union { uint4 q; unsigned short u[8]; } ut, up;
    ut.q = tv;
#pragma unroll
    for (int j = 0; j < 8; ++j) up.u[j] = f2bf(bf2f(ut.u[j]) * svf);
    __syncthreads();
    *(uint4*)&Als[sr * PITCH + sc] = av;
    *(uint4*)&Bls[sr * PITCH + sc] = up.q;
    __syncthreads();
    MFMA_STEP();
  }
  unsigned short* out = ctx + ((size_t)b * 128 + m0) * 512 + n0;
  GEMM_EPILOGUE({ out[(size_t)ml * 512 + nl] = f2bf(vv); });
}

// ---------- K6: out = relu(concat(query, ctx) @ Wo + bo), dual-dtype store ----------
__global__ __launch_bounds__(256) void k_out(
    const unsigned short* __restrict__ query, const unsigned short* __restrict__ ctx,
    const unsigned short* __restrict__ WoT, const unsigned short* __restrict__ bo,
    void* __restrict__ outv, const int* __restrict__ flag) {
  const int m0 = blockIdx.y * 64, n0 = blockIdx.x * 64;
  const int f32mode = *flag;
  GEMM_VARS;
  for (int k0 = 0; k0 < 1536; k0 += 32) {
    uint4 av;
    if (k0 < 1024)
      av = *(const uint4*)&query[(size_t)(m0 + sr) * 1024 + k0 + sc];
    else
      av = *(const uint4*)&ctx[(size_t)(m0 + sr) * 512 + (k0 - 1024) + sc];
    uint4 bv = *(const uint4*)&WoT[(size_t)(n0 + sr) * 1536 + k0 + sc];
    __syncthreads();
    *(uint4*)&Als[sr * PITCH + sc] = av;
    *(uint4*)&Bls[sr * PITCH + sc] = bv;
    __syncthreads();
    MFMA_STEP();
  }
  GEMM_EPILOGUE({
    float v = fmaxf(vv + bf2f(bo[n0 + nl]), 0.f);
    const size_t idx = (size_t)(m0 + ml) * 512 + n0 + nl;
    if (f32mode)
      ((float*)outv)[idx] = v;
    else
      ((unsigned short*)outv)[idx] = f2bf(v);
  });
}

// ---------- launch ----------
extern "C" void kernel_launch(void* const* d_in, const int* in_sizes, int n_in,
                              void* d_out, int out_size, void* d_ws, size_t ws_size,
                              hipStream_t stream) {
  const void* query = d_in[0];
  const void* src = d_in[1];
  const void* trg = d_in[2];
  const void* Wq = d_in[3];
  const void* bq = d_in[4];
  const void* Ws = d_in[5];
  const void* bs = d_in[6];
  const void* Wt = d_in[7];
  const void* bt = d_in[8];
  const void* Wsv = d_in[9];
  const void* bsv = d_in[10];
  const void* Wtv = d_in[11];
  const void* btv = d_in[12];
  const void* Wo = d_in[13];
  const void* bo = d_in[14];

  char* ws = (char*)d_ws;
  size_t off = 0;
  auto alloc = [&](size_t bytes) {
    char* ptr = ws + off;
    off = (off + bytes + 255) & ~(size_t)255;
    return ptr;
  };
  int* flag = (int*)alloc(256);
  unsigned short* qc = (unsigned short*)alloc((size_t)2048 * 1024 * 2);
  unsigned short* srcc = (unsigned short*)alloc((size_t)1024 * 1024 * 2);
  unsigned short* trgc = (unsigned short*)alloc((size_t)1024 * 1024 * 2);
  unsigned short* biasc = (unsigned short*)alloc((size_t)6 * 512 * 2);  // q,s,t,sv,tv,o
  unsigned short* wT = (unsigned short*)alloc((size_t)5 * 524288 * 2);
  unsigned short* woT = (unsigned short*)alloc((size_t)512 * 1536 * 2);
  unsigned short* q_s = (unsigned short*)alloc((size_t)2048 * 512 * 2);
  unsigned short* s_key = (unsigned short*)alloc((size_t)1024 * 512 * 2);
  unsigned short* t_key = (unsigned short*)alloc((size_t)1024 * 512 * 2);
  unsigned short* sv_T = (unsigned short*)alloc((size_t)16 * 512 * 64 * 2);
  unsigned short* tv_T = (unsigned short*)alloc((size_t)16 * 512 * 64 * 2);
  unsigned short* scores = (unsigned short*)alloc((size_t)2048 * 4096 * 2);
  unsigned short* ctx = (unsigned short*)alloc((size_t)2048 * 512 * 2);
  (void)ws_size; (void)in_sizes; (void)n_in; (void)out_size;

  hipLaunchKernelGGL(k_detect, dim3(1), dim3(64), 0, stream, query, flag);

  ConvArgs ca;
  ca.src[0] = query; ca.src[1] = src; ca.src[2] = trg;
  ca.src[3] = bq; ca.src[4] = bs; ca.src[5] = bt; ca.src[6] = bsv; ca.src[7] = btv; ca.src[8] = bo;
  ca.dst[0] = qc; ca.dst[1] = srcc; ca.dst[2] = trgc;
  for (int i = 0; i < 6; ++i) ca.dst[3 + i] = biasc + i * 512;
  ca.n[0] = 2048 * 1024; ca.n[1] = 1024 * 1024; ca.n[2] = 1024 * 1024;
  for (int i = 0; i < 6; ++i) ca.n[3 + i] = 512;
  hipLaunchKernelGGL(k_convert, dim3(512, 1, 9), dim3(256), 0, stream, ca, flag);

  TransArgs ta;
  ta.src[0] = Wq; ta.src[1] = Ws; ta.src[2] = Wt; ta.src[3] = Wsv; ta.src[4] = Wtv; ta.src[5] = Wo;
  for (int i = 0; i < 5; ++i) { ta.dst[i] = wT + (size_t)i * 524288; ta.K[i] = 1024; }
  ta.dst[5] = woT; ta.K[5] = 1536;
  hipLaunchKernelGGL(k_transpose, dim3(16, 48, 6), dim3(256), 0, stream, ta, flag);

  ProjArgs pa;
  pa.A[0] = qc; pa.A[1] = srcc; pa.A[2] = trgc; pa.A[3] = srcc; pa.A[4] = trgc;
  for (int i = 0; i < 5; ++i) pa.W[i] = wT + (size_t)i * 524288;
  for (int i = 0; i < 5; ++i) pa.bias[i] = biasc + i * 512;
  pa.out[0] = q_s; pa.out[1] = s_key; pa.out[2] = t_key; pa.out[3] = sv_T; pa.out[4] = tv_T;
  hipLaunchKernelGGL(k_proj, dim3(8, 32, 5), dim3(256), 0, stream, pa);

  hipLaunchKernelGGL(k_scores, dim3(64, 2, 16), dim3(256), 0, stream, q_s, s_key, t_key, scores);
  hipLaunchKernelGGL(k_softmax, dim3(2048), dim3(256), 0, stream, scores);
  hipLaunchKernelGGL(k_ctx, dim3(8, 2, 16), dim3(256), 0, stream, scores, sv_T, tv_T, ctx);
  hipLaunchKernelGGL(k_out, dim3(8, 32, 1), dim3(256), 0, stream, qc, ctx, woT,
                     biasc + 5 * 512, d_out, flag);
}